// Round 10
// baseline (275.396 us; speedup 1.0000x reference)
//
#include <hip/hip_runtime.h>

// GCNConv: out = D^-1/2 (A + I) D^-1/2 (x W) + bias
// N = 10000, E = 640000, D_IN = D_OUT = 128, fp32 in/out.
//
// Round 10: round-7 structure, 3 plain dispatches (no cooperative launch —
// rounds 5/8/9 showed coop costs tens of µs here). Zero global atomics except
// one 64-increment barrier counter.
//  K1 hist (64 x 1024): packed LDS histogram (out lo16 | in hi16),
//     rank[e] = per-(b,c) in-rank (ushort). Also zeroes the barrier.
//  K2 prep (377 x 1024, one-way software barrier):
//     blocks 0..63:   reduce (dis, indeg, suboff in place) -> threadfence ->
//                     atomicAdd(bar); spin bar==64; then fill csr_src
//                     (ushort src ids) at c*256 + suboff[b][c] + rank[e].
//     blocks 64..376: gemm MAC loop FIRST (no dependency), then spin bar==64,
//                     then g = bf16(acc * dis[row]) (pre-scaled, 32 rows/blk).
//     Deadlock-free: waiters wait only on blocks 0..63 (dispatched first,
//     trivially resident); nobody waits on the gemm blocks.
//  K3 gather (round-7 exact): wave/node, half-wave = 2 edges/step, ushort4
//     bf16 g loads; out = dis[c] * (sum g[src] + g[c]) + bias.

#define NNODES 10000
#define NB 64            // histogram / fill / reduce blocks
#define CAP 256          // CSR slots per node (mean indeg 64, sd 8 -> safe)
#define HBLOCK 1024
#define GEMMB 313        // ceil(10000/32)

__device__ inline unsigned short f2bf(float f) {
    union { float f; unsigned u; } v; v.f = f;
    unsigned r = v.u + 0x7FFFu + ((v.u >> 16) & 1u);   // RNE
    return (unsigned short)(r >> 16);
}
__device__ inline float bf2f(unsigned short h) {
    union { unsigned u; float f; } v; v.u = ((unsigned)h) << 16; return v.f;
}

__global__ __launch_bounds__(HBLOCK) void hist_kernel(
    const int* __restrict__ row, const int* __restrict__ col,
    int* __restrict__ partial, unsigned short* __restrict__ rank,
    int* __restrict__ bar, int N, int E, int EPB) {
    __shared__ int hmem[NNODES];
    const int tid = threadIdx.x, b = blockIdx.x;
    if (b == 0 && tid == 0) *bar = 0;          // reset barrier for K2
    for (int j = tid; j < N; j += HBLOCK) hmem[j] = 0;
    __syncthreads();
    const int e0 = b * EPB, e1 = min(E, e0 + EPB);
    for (int e = e0 + tid; e < e1; e += HBLOCK) {
        int r = row[e], c = col[e];
        atomicAdd(&hmem[r], 1);                                   // out-deg lo16
        unsigned old = atomicAdd((unsigned*)&hmem[c], 0x10000u);  // in-deg hi16
        rank[e] = (unsigned short)(old >> 16);
    }
    __syncthreads();
    for (int j = tid; j < N; j += HBLOCK) partial[b * N + j] = hmem[j];
}

__global__ __launch_bounds__(HBLOCK) void prep_kernel(
    const int* __restrict__ row, const int* __restrict__ col,
    int* __restrict__ partial, const unsigned short* __restrict__ rank,
    float* __restrict__ dis, int* __restrict__ indeg,
    unsigned short* __restrict__ csr_src,
    const float* __restrict__ x, const float* __restrict__ W,
    unsigned short* __restrict__ g, int* __restrict__ bar,
    int N, int E, int EPB, int NPB) {
    __shared__ int lds[NNODES];               // reduce: unused; fill: base
    const int tid = threadIdx.x, b = blockIdx.x;

    if (b < NB) {
        // ---- reduce: nodes [b*NPB, b*NPB+NPB) ----
        int n = b * NPB + tid;
        if (tid < NPB && n < N) {
            int s = 0, run = 0;
#pragma unroll 8
            for (int bb = 0; bb < NB; ++bb) {
                int v = partial[bb * N + n];
                s += v & 0xFFFF;
                partial[bb * N + n] = run;     // becomes suboff[bb][n]
                run += ((unsigned)v) >> 16;
            }
            dis[n] = rsqrtf(1.0f + (float)s);
            indeg[n] = run;
        }
        __threadfence();                       // release suboff/dis/indeg
        __syncthreads();
        if (tid == 0) {
            atomicAdd(bar, 1);
            while (atomicAdd(bar, 0) < NB) __builtin_amdgcn_s_sleep(2);
        }
        __syncthreads();
        __threadfence();                       // acquire other blocks' suboff

        // ---- fill: csr_src[c*CAP + suboff[b][c] + rank[e]] = src ----
        for (int j = tid; j < N; j += HBLOCK)
            lds[j] = (j << 8) + partial[b * N + j];
        __syncthreads();
        const int e0 = b * EPB, e1 = min(E, e0 + EPB);
        for (int e = e0 + tid; e < e1; e += HBLOCK)
            csr_src[lds[col[e]] + (int)rank[e]] = (unsigned short)row[e];
    } else {
        // ---- gemm MAC loop (independent of reduce) ----
        float* xs = (float*)lds;               // 32*128*4 = 16 KB
        const int rowBase = (b - NB) * 32;
        for (int idx = tid; idx < 32 * 128; idx += HBLOCK) {
            int r = rowBase + (idx >> 7);
            xs[idx] = (r < N) ? x[r * 128 + (idx & 127)] : 0.0f;
        }
        __syncthreads();
        const int lr = tid >> 5, c4 = tid & 31;
        const int rr = rowBase + lr;
        const float4* __restrict__ W4 = (const float4*)W;
        float4 acc = make_float4(0.f, 0.f, 0.f, 0.f);
#pragma unroll 8
        for (int k = 0; k < 128; ++k) {
            float xv = xs[lr * 128 + k];
            float4 wv = W4[k * 32 + c4];
            acc.x = fmaf(xv, wv.x, acc.x);
            acc.y = fmaf(xv, wv.y, acc.y);
            acc.z = fmaf(xv, wv.z, acc.z);
            acc.w = fmaf(xv, wv.w, acc.w);
        }
        // ---- wait for reduce (one-way: reduce never waits on us) ----
        if (tid == 0) {
            while (atomicAdd(bar, 0) < NB) __builtin_amdgcn_s_sleep(2);
        }
        __syncthreads();
        __threadfence();                       // acquire dis
        if (rr < N) {
            float d = dis[rr];
            ushort4 o;
            o.x = f2bf(acc.x * d);
            o.y = f2bf(acc.y * d);
            o.z = f2bf(acc.z * d);
            o.w = f2bf(acc.w * d);
            ((ushort4*)g)[rr * 32 + c4] = o;
        }
    }
}

// One wave per destination node. half = lane>>5 picks one of 2 edges per
// step; l32 = lane&31 picks the 4-col bf16 chunk (32 x 8B = one 256B row).
__global__ void gather_kernel(const int* __restrict__ indeg,
                              const unsigned short* __restrict__ csr_src,
                              const unsigned short* __restrict__ g,
                              const float* __restrict__ dis,
                              const float* __restrict__ bias,
                              float* __restrict__ out, int n) {
    const int wave = (blockIdx.x * blockDim.x + threadIdx.x) >> 6;
    const int lane = threadIdx.x & 63;
    if (wave >= n) return;
    const int c = wave;
    const int half = lane >> 5;
    const int l32 = lane & 31;
    const ushort4* __restrict__ g4 = (const ushort4*)g;

    float4 acc = make_float4(0.f, 0.f, 0.f, 0.f);
    if (half == 0) {   // self-loop term: + g[c]
        ushort4 gv = g4[c * 32 + l32];
        acc.x += bf2f(gv.x); acc.y += bf2f(gv.y);
        acc.z += bf2f(gv.z); acc.w += bf2f(gv.w);
    }

    const int start = c << 8;              // c * CAP
    const int end = start + indeg[c];
    for (int base = start; base < end; base += 64) {
        int idx = base + lane;
        int src = (idx < end) ? (int)csr_src[idx] : 0;
        int cnt = min(64, end - base);
#pragma unroll
        for (int t = 0; t < 64; t += 2) {
            int j = t + half;              // half 0: even edges, half 1: odd
            int r = __shfl(src, j);
            if (j < cnt) {
                ushort4 gv = g4[r * 32 + l32];
                acc.x += bf2f(gv.x); acc.y += bf2f(gv.y);
                acc.z += bf2f(gv.z); acc.w += bf2f(gv.w);
            }
        }
    }
    float ox = acc.x + __shfl(acc.x, l32 + 32);
    float oy = acc.y + __shfl(acc.y, l32 + 32);
    float oz = acc.z + __shfl(acc.z, l32 + 32);
    float ow = acc.w + __shfl(acc.w, l32 + 32);
    if (lane < 32) {
        float dc = dis[c];
        float4 bv = ((const float4*)bias)[l32];
        float4 o;
        o.x = fmaf(ox, dc, bv.x);
        o.y = fmaf(oy, dc, bv.y);
        o.z = fmaf(oz, dc, bv.z);
        o.w = fmaf(ow, dc, bv.w);
        ((float4*)out)[c * 32 + l32] = o;
    }
}

extern "C" void kernel_launch(void* const* d_in, const int* in_sizes, int n_in,
                              void* d_out, int out_size, void* d_ws, size_t ws_size,
                              hipStream_t stream) {
    const float* x    = (const float*)d_in[0];
    const int*   ei   = (const int*)d_in[1];
    const float* W    = (const float*)d_in[2];
    const float* bias = (const float*)d_in[3];
    float* out = (float*)d_out;

    int N = in_sizes[0] / 128;     // 10000
    int E = in_sizes[1] / 2;       // 640000
    const int* row = ei;
    const int* col = ei + E;
    int EPB = (E + NB - 1) / NB;   // 10000
    int NPB = (N + NB - 1) / NB;   // 157

    // Workspace (~9.5 MB):
    auto align256 = [](size_t v) { return (v + 255) & ~(size_t)255; };
    char* p = (char*)d_ws;
    int*            partial = (int*)p;            p += align256((size_t)NB * N * 4);   // 2.56 MB
    unsigned short* rank    = (unsigned short*)p; p += align256((size_t)E * 2);        // 1.28 MB
    float*          dis     = (float*)p;          p += align256((size_t)N * 4);
    int*            indeg   = (int*)p;            p += align256((size_t)N * 4);
    int*            bar     = (int*)p;            p += align256(256);
    unsigned short* csr_src = (unsigned short*)p; p += align256((size_t)N * CAP * 2);  // 5.12 MB
    unsigned short* g       = (unsigned short*)p; p += align256((size_t)N * 128 * 2);  // 2.56 MB

    hist_kernel<<<NB, HBLOCK, 0, stream>>>(row, col, partial, rank, bar, N, E, EPB);

    prep_kernel<<<NB + GEMMB, HBLOCK, 0, stream>>>(
        row, col, partial, rank, dis, indeg, csr_src, x, W, g, bar, N, E, EPB, NPB);

    long long gthreads = (long long)N * 64;
    gather_kernel<<<(int)((gthreads + 255) / 256), 256, 0, stream>>>(
        indeg, csr_src, g, dis, bias, out, N);
}

// Round 11
// 161.671 us; speedup vs baseline: 1.7034x; 1.7034x over previous
//
#include <hip/hip_runtime.h>

// GCNConv: out = D^-1/2 (A + I) D^-1/2 (x W) + bias
// N = 10000, E = 640000, D_IN = D_OUT = 128, fp32 in/out.
//
// Round 11: round-7 pipeline (4 plain dispatches — coop & soft barriers all
// regressed in R5/8/9/10), but hist/fill widened to 256 blocks so LDS-atomic
// work spreads over all CUs instead of 64.
//  K1 hist (256 x 512): packed LDS histogram (out lo16 | in hi16),
//     rank[e] = per-(b,c) in-rank (ushort). 2500 edges/block.
//  K2 reduce: dis = rsqrt(1+outdeg); per-block in-counts -> 256-deep
//     exclusive prefix (suboff in place); indeg totals.
//  K3 fillgemm (881 x 512): blocks 0..255 fill csr_src (ushort) at
//     c*256 + suboff[b][c] + rank[e]; blocks 256.. g = bf16((x@W)*dis[row]),
//     16 rows/block.
//  K4 gather: wave/node, half-wave = 2 edges/step, ushort4 bf16 g loads;
//     out = dis[c] * (sum g[src] + g[c]) + bias.

#define NNODES 10000
#define NB 256           // histogram / fill blocks
#define CAP 256          // CSR slots per node (mean indeg 64, sd 8)
#define HBLOCK 512
#define GEMMB 625        // ceil(10000/16)

__device__ inline unsigned short f2bf(float f) {
    union { float f; unsigned u; } v; v.f = f;
    unsigned r = v.u + 0x7FFFu + ((v.u >> 16) & 1u);   // RNE
    return (unsigned short)(r >> 16);
}
__device__ inline float bf2f(unsigned short h) {
    union { unsigned u; float f; } v; v.u = ((unsigned)h) << 16; return v.f;
}

__global__ __launch_bounds__(HBLOCK) void hist_kernel(
    const int* __restrict__ row, const int* __restrict__ col,
    int* __restrict__ partial, unsigned short* __restrict__ rank,
    int N, int E, int EPB) {
    __shared__ int hmem[NNODES];
    const int tid = threadIdx.x, b = blockIdx.x;
    for (int j = tid; j < N; j += HBLOCK) hmem[j] = 0;
    __syncthreads();
    const int e0 = b * EPB, e1 = min(E, e0 + EPB);
    for (int e = e0 + tid; e < e1; e += HBLOCK) {
        int r = row[e], c = col[e];
        atomicAdd(&hmem[r], 1);                                   // out-deg lo16
        unsigned old = atomicAdd((unsigned*)&hmem[c], 0x10000u);  // in-deg hi16
        rank[e] = (unsigned short)(old >> 16);
    }
    __syncthreads();
    for (int j = tid; j < N; j += HBLOCK) partial[b * N + j] = hmem[j];
}

__global__ void reduce_kernel(int* __restrict__ partial, float* __restrict__ dis,
                              int* __restrict__ indeg, int N) {
    int n = blockIdx.x * blockDim.x + threadIdx.x;   // coalesced in n
    if (n >= N) return;
    int s = 0, run = 0;
#pragma unroll 16
    for (int b = 0; b < NB; ++b) {
        int v = partial[b * N + n];
        s += v & 0xFFFF;
        partial[b * N + n] = run;                    // becomes suboff[b][n]
        run += ((unsigned)v) >> 16;
    }
    dis[n] = rsqrtf(1.0f + (float)s);
    indeg[n] = run;
}

__global__ __launch_bounds__(HBLOCK) void fillgemm_kernel(
    const int* __restrict__ row, const int* __restrict__ col,
    const int* __restrict__ partial, const unsigned short* __restrict__ rank,
    const float* __restrict__ dis, unsigned short* __restrict__ csr_src,
    const float* __restrict__ x, const float* __restrict__ W,
    unsigned short* __restrict__ g, int N, int E, int EPB) {
    __shared__ int lds[NNODES];     // fill: base table; gemm: 8 KB x-tile
    const int tid = threadIdx.x;

    if (blockIdx.x < NB) {
        // ---- fill: atomic-free CSR scatter (ushort src ids) ----
        const int b = blockIdx.x;
        for (int j = tid; j < N; j += HBLOCK)
            lds[j] = (j << 8) + partial[b * N + j];   // c*CAP + suboff[b][c]
        __syncthreads();
        const int e0 = b * EPB, e1 = min(E, e0 + EPB);
        for (int e = e0 + tid; e < e1; e += HBLOCK)
            csr_src[lds[col[e]] + (int)rank[e]] = (unsigned short)row[e];
    } else {
        // ---- gemm: g = bf16((x @ W) * dis[row]), 16 rows/block ----
        float* xs = (float*)lds;                       // 16*128*4 = 8 KB
        const int rowBase = (blockIdx.x - NB) * 16;
        for (int idx = tid; idx < 16 * 128; idx += HBLOCK) {
            int r = rowBase + (idx >> 7);
            xs[idx] = (r < N) ? x[r * 128 + (idx & 127)] : 0.0f;
        }
        __syncthreads();
        const int lr = tid >> 5, c4 = tid & 31;        // lr 0..15
        const int rr = rowBase + lr;
        const float4* __restrict__ W4 = (const float4*)W;
        float4 acc = make_float4(0.f, 0.f, 0.f, 0.f);
#pragma unroll 8
        for (int k = 0; k < 128; ++k) {
            float xv = xs[lr * 128 + k];
            float4 wv = W4[k * 32 + c4];
            acc.x = fmaf(xv, wv.x, acc.x);
            acc.y = fmaf(xv, wv.y, acc.y);
            acc.z = fmaf(xv, wv.z, acc.z);
            acc.w = fmaf(xv, wv.w, acc.w);
        }
        if (rr < N) {
            float d = dis[rr];
            ushort4 o;
            o.x = f2bf(acc.x * d);
            o.y = f2bf(acc.y * d);
            o.z = f2bf(acc.z * d);
            o.w = f2bf(acc.w * d);
            ((ushort4*)g)[rr * 32 + c4] = o;
        }
    }
}

// One wave per destination node. half = lane>>5 picks one of 2 edges per
// step; l32 = lane&31 picks the 4-col bf16 chunk (32 x 8B = one 256B row).
__global__ void gather_kernel(const int* __restrict__ indeg,
                              const unsigned short* __restrict__ csr_src,
                              const unsigned short* __restrict__ g,
                              const float* __restrict__ dis,
                              const float* __restrict__ bias,
                              float* __restrict__ out, int n) {
    const int wave = (blockIdx.x * blockDim.x + threadIdx.x) >> 6;
    const int lane = threadIdx.x & 63;
    if (wave >= n) return;
    const int c = wave;
    const int half = lane >> 5;
    const int l32 = lane & 31;
    const ushort4* __restrict__ g4 = (const ushort4*)g;

    float4 acc = make_float4(0.f, 0.f, 0.f, 0.f);
    if (half == 0) {   // self-loop term: + g[c]
        ushort4 gv = g4[c * 32 + l32];
        acc.x += bf2f(gv.x); acc.y += bf2f(gv.y);
        acc.z += bf2f(gv.z); acc.w += bf2f(gv.w);
    }

    const int start = c << 8;              // c * CAP
    const int end = start + indeg[c];
    for (int base = start; base < end; base += 64) {
        int idx = base + lane;
        int src = (idx < end) ? (int)csr_src[idx] : 0;
        int cnt = min(64, end - base);
#pragma unroll
        for (int t = 0; t < 64; t += 2) {
            int j = t + half;              // half 0: even edges, half 1: odd
            int r = __shfl(src, j);
            if (j < cnt) {
                ushort4 gv = g4[r * 32 + l32];
                acc.x += bf2f(gv.x); acc.y += bf2f(gv.y);
                acc.z += bf2f(gv.z); acc.w += bf2f(gv.w);
            }
        }
    }
    float ox = acc.x + __shfl(acc.x, l32 + 32);
    float oy = acc.y + __shfl(acc.y, l32 + 32);
    float oz = acc.z + __shfl(acc.z, l32 + 32);
    float ow = acc.w + __shfl(acc.w, l32 + 32);
    if (lane < 32) {
        float dc = dis[c];
        float4 bv = ((const float4*)bias)[l32];
        float4 o;
        o.x = fmaf(ox, dc, bv.x);
        o.y = fmaf(oy, dc, bv.y);
        o.z = fmaf(oz, dc, bv.z);
        o.w = fmaf(ow, dc, bv.w);
        ((float4*)out)[c * 32 + l32] = o;
    }
}

extern "C" void kernel_launch(void* const* d_in, const int* in_sizes, int n_in,
                              void* d_out, int out_size, void* d_ws, size_t ws_size,
                              hipStream_t stream) {
    const float* x    = (const float*)d_in[0];
    const int*   ei   = (const int*)d_in[1];
    const float* W    = (const float*)d_in[2];
    const float* bias = (const float*)d_in[3];
    float* out = (float*)d_out;

    int N = in_sizes[0] / 128;     // 10000
    int E = in_sizes[1] / 2;       // 640000
    const int* row = ei;
    const int* col = ei + E;
    int EPB = (E + NB - 1) / NB;   // 2500

    // Workspace (~20 MB):
    auto align256 = [](size_t v) { return (v + 255) & ~(size_t)255; };
    char* p = (char*)d_ws;
    int*            partial = (int*)p;            p += align256((size_t)NB * N * 4);   // 10.24 MB
    unsigned short* rank    = (unsigned short*)p; p += align256((size_t)E * 2);        // 1.28 MB
    float*          dis     = (float*)p;          p += align256((size_t)N * 4);
    int*            indeg   = (int*)p;            p += align256((size_t)N * 4);
    unsigned short* csr_src = (unsigned short*)p; p += align256((size_t)N * CAP * 2);  // 5.12 MB
    unsigned short* g       = (unsigned short*)p; p += align256((size_t)N * 128 * 2);  // 2.56 MB

    hist_kernel<<<NB, HBLOCK, 0, stream>>>(row, col, partial, rank, N, E, EPB);
    reduce_kernel<<<(N + 255) / 256, 256, 0, stream>>>(partial, dis, indeg, N);

    fillgemm_kernel<<<NB + GEMMB, HBLOCK, 0, stream>>>(
        row, col, partial, rank, dis, csr_src, x, W, g, N, E, EPB);

    long long gthreads = (long long)N * 64;
    gather_kernel<<<(int)((gthreads + 255) / 256), 256, 0, stream>>>(
        indeg, csr_src, g, dis, bias, out, N);
}